// Round 7
// baseline (156.950 us; speedup 1.0000x reference)
//
#include <hip/hip_runtime.h>
#include <hip/hip_bf16.h>
#include <math.h>

#define FEAT 384
#define FFN  768
#define ZDIM 384
#define HID  192
#define BB   4
#define NN   128
#define BN   (BB*NN)   // 512 rows

__device__ __forceinline__ float gelu_exact(float x) {
    // jax.nn.gelu(approximate=False) == 0.5*x*(1+erf(x/sqrt(2)))
    return 0.5f * x * (1.0f + erff(x * 0.70710678118654752440f));
}

__device__ __forceinline__ float bflo(unsigned u) { return __uint_as_float(u << 16); }
__device__ __forceinline__ float bfhi(unsigned u) { return __uint_as_float(u & 0xFFFF0000u); }

template<bool F32>
__device__ __forceinline__ float ldg(const void* p, int i) {
    if constexpr (F32) return ((const float*)p)[i];
    return __uint_as_float(((unsigned)((const unsigned short*)p)[i]) << 16);
}

__device__ __forceinline__ unsigned pack2(float a, float b) {
    __hip_bfloat16 ba = __float2bfloat16(a), bb = __float2bfloat16(b);
    unsigned short ua, ub;
    __builtin_memcpy(&ua, &ba, 2);
    __builtin_memcpy(&ub, &bb, 2);
    return (unsigned)ua | ((unsigned)ub << 16);
}

template<bool F32>
__device__ __forceinline__ void st8(void* p, size_t off, const float v[8]) {
    if constexpr (F32) {
        *(float4*)((float*)p + off)     = make_float4(v[0], v[1], v[2], v[3]);
        *(float4*)((float*)p + off + 4) = make_float4(v[4], v[5], v[6], v[7]);
    } else {
        uint4 u;
        u.x = pack2(v[0], v[1]); u.y = pack2(v[2], v[3]);
        u.z = pack2(v[4], v[5]); u.w = pack2(v[6], v[7]);
        *(uint4*)((unsigned short*)p + off) = u;
    }
}

// 8-element weight vector: one 16B load (bf16) / two 16B loads (fp32)
template<bool F32> struct V8;
template<> struct V8<true> {
    float4 a, b;
    __device__ __forceinline__ void load(const void* p, size_t off) {
        a = *(const float4*)((const float*)p + off);
        b = *(const float4*)((const float*)p + off + 4);
    }
    __device__ __forceinline__ float g(int i) const {
        return (i < 4) ? (&a.x)[i] : (&b.x)[i - 4];
    }
};
template<> struct V8<false> {
    uint4 u;
    __device__ __forceinline__ void load(const void* p, size_t off) {
        u = *(const uint4*)((const unsigned short*)p + off);
    }
    __device__ __forceinline__ float g(int i) const {
        const unsigned w = (&u.x)[i >> 1];
        return (i & 1) ? bfhi(w) : bflo(w);
    }
};
// 4-element weight vector: 8B load (bf16) / 16B load (fp32)
template<bool F32> struct V4;
template<> struct V4<true> {
    float4 a;
    __device__ __forceinline__ void load(const void* p, size_t off) {
        a = *(const float4*)((const float*)p + off);
    }
    __device__ __forceinline__ float g(int i) const { return (&a.x)[i]; }
};
template<> struct V4<false> {
    uint2 u;
    __device__ __forceinline__ void load(const void* p, size_t off) {
        u = *(const uint2*)((const unsigned short*)p + off);
    }
    __device__ __forceinline__ float g(int i) const {
        const unsigned w = (&u.x)[i >> 1];
        return (i & 1) ? bfhi(w) : bflo(w);
    }
};

// dtype detect from ln_w (== ones): fp32 1.0f low u16 = 0x0000; bf16 = 0x3F80.
__device__ __forceinline__ bool is_f32(const void* ln_w) {
    return ((const unsigned short*)ln_w)[0] == 0;
}

// ---- block reductions over 384 threads (6 wave64); sm holds 12 floats ----
__device__ __forceinline__ float block_sum(float v, float* sm) {
    for (int o = 32; o > 0; o >>= 1) v += __shfl_down(v, o, 64);
    const int lane = threadIdx.x & 63, w = threadIdx.x >> 6;
    __syncthreads();
    if (lane == 0) sm[w] = v;
    __syncthreads();
    return sm[0] + sm[1] + sm[2] + sm[3] + sm[4] + sm[5];
}
__device__ __forceinline__ float2 block_sum2(float vx, float vy, float* sm) {
    for (int o = 32; o > 0; o >>= 1) {
        vx += __shfl_down(vx, o, 64);
        vy += __shfl_down(vy, o, 64);
    }
    const int lane = threadIdx.x & 63, w = threadIdx.x >> 6;
    __syncthreads();
    if (lane == 0) { sm[w] = vx; sm[w + 6] = vy; }
    __syncthreads();
    return make_float2(sm[0] + sm[1] + sm[2] + sm[3] + sm[4] + sm[5],
                       sm[6] + sm[7] + sm[8] + sm[9] + sm[10] + sm[11]);
}
__device__ __forceinline__ float block_max(float v, float* sm) {
    for (int o = 32; o > 0; o >>= 1) v = fmaxf(v, __shfl_down(v, o, 64));
    const int lane = threadIdx.x & 63, w = threadIdx.x >> 6;
    __syncthreads();
    if (lane == 0) sm[w] = v;
    __syncthreads();
    return fmaxf(fmaxf(fmaxf(sm[0], sm[1]), fmaxf(sm[2], sm[3])), fmaxf(sm[4], sm[5]));
}

// ============ K1: 1024 blocks = 512 rows x 2 col-halves of U ============
// h=0 block: U cols [0,384) -> xh, store, exit.
// h=1 block: U cols [384,768) -> z-raw -> LN -> encoder -> decoder -> dots.
template<bool F32>
__device__ void rows_body(
    const void* __restrict__ x, const void* __restrict__ U_w,
    const void* __restrict__ U_b, const void* __restrict__ ln_w,
    const void* __restrict__ ln_b, const void* __restrict__ enc_w,
    const void* __restrict__ enc_b, const void* __restrict__ dec_w,
    const void* __restrict__ dec_b,
    float* __restrict__ xh, float* __restrict__ d0, float* __restrict__ diag)
{
    const int r = blockIdx.x >> 1;
    const int h = blockIdx.x & 1;
    const int t = threadIdx.x;
    __shared__ float xs[FEAT];
    __shared__ float zs[ZDIM];
    __shared__ float hid[HID];
    __shared__ float gh[HID];
    __shared__ float part[7 * 384];   // split-K partials (reused per stage)
    __shared__ float sm[12];

    xs[t] = ldg<F32>(x, r * FEAT + t);
    if (h && t < HID) gh[t] = gelu_exact(ldg<F32>(enc_b, t));   // for AE(0)
    __syncthreads();

    // ---------- U half: cg=t%48 -> 8 cols; kh=t/48 -> K chunk of 48 ----------
    const int cg = t % 48, kh = t / 48;
    const int cLoc = 8 * cg;               // 0..376 within this half
    const int cGlob = 384 * h + cLoc;
    const int kb = 48 * kh;
    float acc[8] = {0,0,0,0,0,0,0,0};
    {
        V8<F32> wa[8], wb[8];
        #pragma unroll
        for (int j = 0; j < 8; j++) wa[j].load(U_w, (size_t)(kb + j) * FFN + cGlob);
        for (int k0 = kb; k0 < kb + 48; k0 += 16) {
            #pragma unroll
            for (int j = 0; j < 8; j++) wb[j].load(U_w, (size_t)(k0 + 8 + j) * FFN + cGlob);
            #pragma unroll
            for (int j = 0; j < 8; j++) {
                const float xv = xs[k0 + j];
                #pragma unroll
                for (int i = 0; i < 8; i++) acc[i] = fmaf(xv, wa[j].g(i), acc[i]);
            }
            if (k0 + 16 < kb + 48) {
                #pragma unroll
                for (int j = 0; j < 8; j++) wa[j].load(U_w, (size_t)(k0 + 16 + j) * FFN + cGlob);
            }
            #pragma unroll
            for (int j = 0; j < 8; j++) {
                const float xv = xs[k0 + 8 + j];
                #pragma unroll
                for (int i = 0; i < 8; i++) acc[i] = fmaf(xv, wb[j].g(i), acc[i]);
            }
        }
    }
    if (kh > 0) {
        float* p = &part[(kh - 1) * 384 + cLoc];
        #pragma unroll
        for (int i = 0; i < 8; i++) p[i] = acc[i];
    }
    __syncthreads();

    float hv[8];
    float s1 = 0.f, s2 = 0.f;
    if (kh == 0) {
        #pragma unroll
        for (int i = 0; i < 8; i++) {
            float v = acc[i] + ldg<F32>(U_b, cGlob + i);
            #pragma unroll
            for (int kk = 0; kk < 7; kk++) v += part[kk * 384 + cLoc + i];
            v = gelu_exact(v);
            hv[i] = v;
            s1 += v; s2 += v * v;
        }
        if (h == 0) {
            *(float4*)(xh + (size_t)r * ZDIM + cLoc)     = make_float4(hv[0], hv[1], hv[2], hv[3]);
            *(float4*)(xh + (size_t)r * ZDIM + cLoc + 4) = make_float4(hv[4], hv[5], hv[6], hv[7]);
        }
    }
    if (h == 0) return;   // xh-half blocks done (block-uniform exit)

    // ---------- LayerNorm ----------
    const float2 S = block_sum2(s1, s2, sm);
    const float mu = S.x * (1.0f / ZDIM);
    const float rs = rsqrtf(S.y * (1.0f / ZDIM) - mu * mu + 1e-5f);
    if (kh == 0) {
        #pragma unroll
        for (int i = 0; i < 8; i++) {
            const int zc = cLoc + i;
            zs[zc] = (hv[i] - mu) * rs * ldg<F32>(ln_w, zc) + ldg<F32>(ln_b, zc);
        }
    }
    __syncthreads();

    // ---------- encoder: cgE=t%48 -> 4 cols of 192; khE=t/48 -> K chunk 48 ----------
    {
        const int cgE = t % 48, khE = t / 48;
        const int cE = 4 * cgE, kbE = 48 * khE;
        float ea[4] = {0,0,0,0};
        V4<F32> va[8], vb[8];
        #pragma unroll
        for (int j = 0; j < 8; j++) va[j].load(enc_w, (size_t)(kbE + j) * HID + cE);
        for (int k0 = kbE; k0 < kbE + 48; k0 += 16) {
            #pragma unroll
            for (int j = 0; j < 8; j++) vb[j].load(enc_w, (size_t)(k0 + 8 + j) * HID + cE);
            #pragma unroll
            for (int j = 0; j < 8; j++) {
                const float zv = zs[k0 + j];
                #pragma unroll
                for (int i = 0; i < 4; i++) ea[i] = fmaf(zv, va[j].g(i), ea[i]);
            }
            if (k0 + 16 < kbE + 48) {
                #pragma unroll
                for (int j = 0; j < 8; j++) va[j].load(enc_w, (size_t)(k0 + 16 + j) * HID + cE);
            }
            #pragma unroll
            for (int j = 0; j < 8; j++) {
                const float zv = zs[k0 + 8 + j];
                #pragma unroll
                for (int i = 0; i < 4; i++) ea[i] = fmaf(zv, vb[j].g(i), ea[i]);
            }
        }
        if (khE > 0) {
            float* p = &part[(khE - 1) * 192 + cE];
            #pragma unroll
            for (int i = 0; i < 4; i++) p[i] = ea[i];
        }
        __syncthreads();
        if (khE == 0) {
            #pragma unroll
            for (int i = 0; i < 4; i++) {
                const int c = cE + i;
                float v = ea[i] + ldg<F32>(enc_b, c);
                #pragma unroll
                for (int kk = 0; kk < 7; kk++) v += part[kk * 192 + c];
                hid[c] = gelu_exact(v);
            }
        }
        __syncthreads();
    }

    // ---------- decoder: cgD=t%96 -> 4 cols of 384; khD=t/96 -> K chunk 48 ----------
    {
        const int cgD = t % 96, khD = t / 96;
        const int cD = 4 * cgD, kbD = 48 * khD;
        float aa[4] = {0,0,0,0}, ac[4] = {0,0,0,0};
        V4<F32> va[8], vb[8];
        #pragma unroll
        for (int j = 0; j < 8; j++) va[j].load(dec_w, (size_t)(kbD + j) * ZDIM + cD);
        for (int k0 = kbD; k0 < kbD + 48; k0 += 16) {
            #pragma unroll
            for (int j = 0; j < 8; j++) vb[j].load(dec_w, (size_t)(k0 + 8 + j) * ZDIM + cD);
            #pragma unroll
            for (int j = 0; j < 8; j++) {
                const float hvv = hid[k0 + j], gv = gh[k0 + j];
                #pragma unroll
                for (int i = 0; i < 4; i++) {
                    const float w = va[j].g(i);
                    aa[i] = fmaf(hvv, w, aa[i]);
                    ac[i] = fmaf(gv, w, ac[i]);
                }
            }
            if (k0 + 16 < kbD + 48) {
                #pragma unroll
                for (int j = 0; j < 8; j++) va[j].load(dec_w, (size_t)(k0 + 16 + j) * ZDIM + cD);
            }
            #pragma unroll
            for (int j = 0; j < 8; j++) {
                const float hvv = hid[k0 + 8 + j], gv = gh[k0 + 8 + j];
                #pragma unroll
                for (int i = 0; i < 4; i++) {
                    const float w = vb[j].g(i);
                    aa[i] = fmaf(hvv, w, aa[i]);
                    ac[i] = fmaf(gv, w, ac[i]);
                }
            }
        }
        if (khD > 0) {
            float* p = &part[(khD - 1) * 768 + cD];
            #pragma unroll
            for (int i = 0; i < 4; i++) { p[i] = aa[i]; p[384 + i] = ac[i]; }
        }
        __syncthreads();
        float pd = 0.f, pe = 0.f;
        if (khD == 0) {
            #pragma unroll
            for (int i = 0; i < 4; i++) {
                const int c = cD + i;
                const float dbv = ldg<F32>(dec_b, c);
                float v = aa[i] + dbv, w = ac[i] + dbv;
                #pragma unroll
                for (int kk = 0; kk < 3; kk++) {
                    v += part[kk * 768 + c];
                    w += part[kk * 768 + 384 + c];
                }
                const float zv = zs[c];
                pd = fmaf(v, zv, pd);
                pe = fmaf(w, zv, pe);
            }
        }
        const float2 D = block_sum2(pd, pe, sm);
        if (t == 0) { diag[r] = D.x; d0[r] = D.y; }
    }
}

__global__ __launch_bounds__(384) void k_rows(
    const void* x, const void* U_w, const void* U_b,
    const void* ln_w, const void* ln_b,
    const void* enc_w, const void* enc_b,
    const void* dec_w, const void* dec_b,
    float* xh, float* d0, float* diag)
{
    if (is_f32(ln_w))
        rows_body<true >(x, U_w, U_b, ln_w, ln_b, enc_w, enc_b, dec_w, dec_b, xh, d0, diag);
    else
        rows_body<false>(x, U_w, U_b, ln_w, ln_b, enc_w, enc_b, dec_w, dec_b, xh, d0, diag);
}

// ============ K2: 512 blocks, 1 row: batch stats + combine + V (split-K) ============
template<bool F32>
__device__ void out_body(
    const float* __restrict__ d0, const float* __restrict__ diag,
    const float* __restrict__ xh,
    const void* __restrict__ V_w, const void* __restrict__ V_b,
    void* __restrict__ out)
{
    const int r = blockIdx.x;
    const int b = r >> 7;
    const int t = threadIdx.x;
    __shared__ float e0s[NN];
    __shared__ float as[ZDIM];
    __shared__ float pv[7 * 384];
    __shared__ float sm[12];

    // batch softmax stats (redundant per block)
    float d0v = -INFINITY, dgv = -INFINITY;
    if (t < NN) { d0v = d0[b * NN + t]; dgv = diag[b * NN + t]; }
    const float m = block_max(fmaxf(d0v, dgv), sm);
    float e0v = 0.f;
    if (t < NN) { e0v = expf(d0v - m); e0s[t] = e0v; }
    const float S = block_sum(e0v, sm);

    const float e00 = expf(d0[r] - m);
    const float ed0 = expf(diag[r] - m);
    const float inv = 1.0f / (S - e00 + ed0);

    // base_t = sum_j e0s[j] * xh[b,j,t]  (16-deep ping-pong)
    float acc = 0.f;
    {
        const float* xp = xh + (size_t)b * NN * ZDIM + t;
        float wa[16], wb[16];
        #pragma unroll
        for (int j = 0; j < 16; j++) wa[j] = xp[(size_t)j * ZDIM];
        for (int j0 = 0; j0 < NN; j0 += 32) {
            #pragma unroll
            for (int j = 0; j < 16; j++) wb[j] = xp[(size_t)(j0 + 16 + j) * ZDIM];
            #pragma unroll
            for (int j = 0; j < 16; j++) acc = fmaf(e0s[j0 + j], wa[j], acc);
            if (j0 + 32 < NN) {
                #pragma unroll
                for (int j = 0; j < 16; j++) wa[j] = xp[(size_t)(j0 + 32 + j) * ZDIM];
            }
            #pragma unroll
            for (int j = 0; j < 16; j++) acc = fmaf(e0s[j0 + 16 + j], wb[j], acc);
        }
    }
    as[t] = (acc + (ed0 - e00) * xh[(size_t)r * ZDIM + t]) * inv;
    __syncthreads();

    // V: cg=t%48 -> 8 cols of 384; kh=t/48 -> K chunk of 48
    const int cg = t % 48, kh = t / 48;
    const int cV = 8 * cg, kb = 48 * kh;
    float a8[8] = {0,0,0,0,0,0,0,0};
    {
        V8<F32> va[8], vb[8];
        #pragma unroll
        for (int j = 0; j < 8; j++) va[j].load(V_w, (size_t)(kb + j) * FEAT + cV);
        for (int f0 = kb; f0 < kb + 48; f0 += 16) {
            #pragma unroll
            for (int j = 0; j < 8; j++) vb[j].load(V_w, (size_t)(f0 + 8 + j) * FEAT + cV);
            #pragma unroll
            for (int j = 0; j < 8; j++) {
                const float s0 = as[f0 + j];
                #pragma unroll
                for (int i = 0; i < 8; i++) a8[i] = fmaf(s0, va[j].g(i), a8[i]);
            }
            if (f0 + 16 < kb + 48) {
                #pragma unroll
                for (int j = 0; j < 8; j++) va[j].load(V_w, (size_t)(f0 + 16 + j) * FEAT + cV);
            }
            #pragma unroll
            for (int j = 0; j < 8; j++) {
                const float s0 = as[f0 + 8 + j];
                #pragma unroll
                for (int i = 0; i < 8; i++) a8[i] = fmaf(s0, vb[j].g(i), a8[i]);
            }
        }
    }
    if (kh > 0) {
        float* p = &pv[(kh - 1) * 384 + cV];
        #pragma unroll
        for (int i = 0; i < 8; i++) p[i] = a8[i];
    }
    __syncthreads();
    if (kh == 0) {
        float o[8];
        #pragma unroll
        for (int i = 0; i < 8; i++) {
            const int c = cV + i;
            float u = a8[i] + ldg<F32>(V_b, c);
            #pragma unroll
            for (int kk = 0; kk < 7; kk++) u += pv[kk * 384 + c];
            o[i] = u;
        }
        st8<F32>(out, (size_t)r * FEAT + cV, o);
    }
}

__global__ __launch_bounds__(384) void k_out(
    const void* ln_w,
    const float* d0, const float* diag, const float* xh,
    const void* V_w, const void* V_b, void* out)
{
    if (is_f32(ln_w))
        out_body<true >(d0, diag, xh, V_w, V_b, out);
    else
        out_body<false>(d0, diag, xh, V_w, V_b, out);
}

extern "C" void kernel_launch(void* const* d_in, const int* in_sizes, int n_in,
                              void* d_out, int out_size, void* d_ws, size_t ws_size,
                              hipStream_t stream) {
    const void* x     = d_in[0];
    const void* U_w   = d_in[1];
    const void* U_b   = d_in[2];
    const void* ln_w  = d_in[3];
    const void* ln_b  = d_in[4];
    const void* enc_w = d_in[5];
    const void* enc_b = d_in[6];
    const void* dec_w = d_in[7];
    const void* dec_b = d_in[8];
    const void* V_w   = d_in[9];
    const void* V_b   = d_in[10];

    // workspace layout (fp32)
    float* ws   = (float*)d_ws;
    float* xh   = ws;                     // 512*384
    float* d0   = xh + (size_t)BN * ZDIM; // 512
    float* diag = d0 + BN;                // 512

    k_rows<<<2 * BN, 384, 0, stream>>>(x, U_w, U_b, ln_w, ln_b, enc_w, enc_b,
                                       dec_w, dec_b, xh, d0, diag);
    k_out<<<BN, 384, 0, stream>>>(ln_w, d0, diag, xh, V_w, V_b, d_out);
}

// Round 8
// 138.555 us; speedup vs baseline: 1.1328x; 1.1328x over previous
//
#include <hip/hip_runtime.h>
#include <hip/hip_bf16.h>
#include <math.h>

#define FEAT 384
#define FFN  768
#define ZDIM 384
#define HID  192
#define BB   4
#define NN   128
#define BN   (BB*NN)   // 512 rows

__device__ __forceinline__ float gelu_exact(float x) {
    // jax.nn.gelu(approximate=False) == 0.5*x*(1+erf(x/sqrt(2)))
    return 0.5f * x * (1.0f + erff(x * 0.70710678118654752440f));
}

__device__ __forceinline__ float bflo(unsigned u) { return __uint_as_float(u << 16); }
__device__ __forceinline__ float bfhi(unsigned u) { return __uint_as_float(u & 0xFFFF0000u); }

template<bool F32>
__device__ __forceinline__ float ldg(const void* p, int i) {
    if constexpr (F32) return ((const float*)p)[i];
    return __uint_as_float(((unsigned)((const unsigned short*)p)[i]) << 16);
}

__device__ __forceinline__ unsigned pack2(float a, float b) {
    __hip_bfloat16 ba = __float2bfloat16(a), bb = __float2bfloat16(b);
    unsigned short ua, ub;
    __builtin_memcpy(&ua, &ba, 2);
    __builtin_memcpy(&ub, &bb, 2);
    return (unsigned)ua | ((unsigned)ub << 16);
}

template<bool F32>
__device__ __forceinline__ void st8(void* p, size_t off, const float v[8]) {
    if constexpr (F32) {
        *(float4*)((float*)p + off)     = make_float4(v[0], v[1], v[2], v[3]);
        *(float4*)((float*)p + off + 4) = make_float4(v[4], v[5], v[6], v[7]);
    } else {
        uint4 u;
        u.x = pack2(v[0], v[1]); u.y = pack2(v[2], v[3]);
        u.z = pack2(v[4], v[5]); u.w = pack2(v[6], v[7]);
        *(uint4*)((unsigned short*)p + off) = u;
    }
}

// 8-element weight vector: one 16B load (bf16) / two 16B loads (fp32)
template<bool F32> struct V8;
template<> struct V8<true> {
    float4 a, b;
    __device__ __forceinline__ void load(const void* p, size_t off) {
        a = *(const float4*)((const float*)p + off);
        b = *(const float4*)((const float*)p + off + 4);
    }
    __device__ __forceinline__ float g(int i) const {
        return (i < 4) ? (&a.x)[i] : (&b.x)[i - 4];
    }
};
template<> struct V8<false> {
    uint4 u;
    __device__ __forceinline__ void load(const void* p, size_t off) {
        u = *(const uint4*)((const unsigned short*)p + off);
    }
    __device__ __forceinline__ float g(int i) const {
        const unsigned w = (&u.x)[i >> 1];
        return (i & 1) ? bfhi(w) : bflo(w);
    }
};
// 4-element weight vector: 8B load (bf16) / 16B load (fp32)
template<bool F32> struct V4;
template<> struct V4<true> {
    float4 a;
    __device__ __forceinline__ void load(const void* p, size_t off) {
        a = *(const float4*)((const float*)p + off);
    }
    __device__ __forceinline__ float g(int i) const { return (&a.x)[i]; }
};
template<> struct V4<false> {
    uint2 u;
    __device__ __forceinline__ void load(const void* p, size_t off) {
        u = *(const uint2*)((const unsigned short*)p + off);
    }
    __device__ __forceinline__ float g(int i) const {
        const unsigned w = (&u.x)[i >> 1];
        return (i & 1) ? bfhi(w) : bflo(w);
    }
};

// dtype detect from ln_w (== ones): fp32 1.0f low u16 = 0x0000; bf16 = 0x3F80.
__device__ __forceinline__ bool is_f32(const void* ln_w) {
    return ((const unsigned short*)ln_w)[0] == 0;
}

// ---- block reductions over 384 threads (6 wave64); sm holds 12 floats ----
__device__ __forceinline__ float block_sum(float v, float* sm) {
    for (int o = 32; o > 0; o >>= 1) v += __shfl_down(v, o, 64);
    const int lane = threadIdx.x & 63, w = threadIdx.x >> 6;
    __syncthreads();
    if (lane == 0) sm[w] = v;
    __syncthreads();
    return sm[0] + sm[1] + sm[2] + sm[3] + sm[4] + sm[5];
}
__device__ __forceinline__ float2 block_sum2(float vx, float vy, float* sm) {
    for (int o = 32; o > 0; o >>= 1) {
        vx += __shfl_down(vx, o, 64);
        vy += __shfl_down(vy, o, 64);
    }
    const int lane = threadIdx.x & 63, w = threadIdx.x >> 6;
    __syncthreads();
    if (lane == 0) { sm[w] = vx; sm[w + 6] = vy; }
    __syncthreads();
    return make_float2(sm[0] + sm[1] + sm[2] + sm[3] + sm[4] + sm[5],
                       sm[6] + sm[7] + sm[8] + sm[9] + sm[10] + sm[11]);
}
__device__ __forceinline__ float block_max(float v, float* sm) {
    for (int o = 32; o > 0; o >>= 1) v = fmaxf(v, __shfl_down(v, o, 64));
    const int lane = threadIdx.x & 63, w = threadIdx.x >> 6;
    __syncthreads();
    if (lane == 0) sm[w] = v;
    __syncthreads();
    return fmaxf(fmaxf(fmaxf(sm[0], sm[1]), fmaxf(sm[2], sm[3])), fmaxf(sm[4], sm[5]));
}

// ============ K1: 512 blocks, 1 row: U + LN + AE + dots; split-K everywhere,
//               conflict-free transposed partial layout part[kh][i*G + cg] ============
template<bool F32>
__device__ void rows_body(
    const void* __restrict__ x, const void* __restrict__ U_w,
    const void* __restrict__ U_b, const void* __restrict__ ln_w,
    const void* __restrict__ ln_b, const void* __restrict__ enc_w,
    const void* __restrict__ enc_b, const void* __restrict__ dec_w,
    const void* __restrict__ dec_b,
    float* __restrict__ xh, float* __restrict__ d0, float* __restrict__ diag)
{
    const int r = blockIdx.x;
    const int t = threadIdx.x;
    __shared__ float xs[FEAT];
    __shared__ float zs[ZDIM];
    __shared__ float hid[HID];
    __shared__ float gh[HID];
    __shared__ float part[2304];   // U: 3*768, enc: 7*192, dec: 3*768
    __shared__ float sm[12];

    xs[t] = ldg<F32>(x, r * FEAT + t);
    if (t < HID) gh[t] = gelu_exact(ldg<F32>(enc_b, t));   // for AE(0)
    __syncthreads();

    // ---------- U: cg=t%96 -> 8 cols of 768; kh=t/96 -> K chunk of 96 ----------
    const int cg = t % 96, kh = t / 96;
    const int cU = 8 * cg;
    const int kb = 96 * kh;
    float acc[8] = {0,0,0,0,0,0,0,0};
    {
        V8<F32> wa[8], wb[8];
        #pragma unroll
        for (int j = 0; j < 8; j++) wa[j].load(U_w, (size_t)(kb + j) * FFN + cU);
        for (int k0 = kb; k0 < kb + 96; k0 += 16) {
            #pragma unroll
            for (int j = 0; j < 8; j++) wb[j].load(U_w, (size_t)(k0 + 8 + j) * FFN + cU);
            #pragma unroll
            for (int j = 0; j < 8; j++) {
                const float xv = xs[k0 + j];
                #pragma unroll
                for (int i = 0; i < 8; i++) acc[i] = fmaf(xv, wa[j].g(i), acc[i]);
            }
            if (k0 + 16 < kb + 96) {
                #pragma unroll
                for (int j = 0; j < 8; j++) wa[j].load(U_w, (size_t)(k0 + 16 + j) * FFN + cU);
            }
            #pragma unroll
            for (int j = 0; j < 8; j++) {
                const float xv = xs[k0 + 8 + j];
                #pragma unroll
                for (int i = 0; i < 8; i++) acc[i] = fmaf(xv, wb[j].g(i), acc[i]);
            }
        }
    }
    if (kh > 0) {
        float* p = &part[(kh - 1) * 768 + cg];
        #pragma unroll
        for (int i = 0; i < 8; i++) p[i * 96] = acc[i];   // transposed: lanes contiguous
    }
    __syncthreads();

    float hv[8];
    float s1 = 0.f, s2 = 0.f;
    if (kh == 0) {
        #pragma unroll
        for (int i = 0; i < 8; i++) {
            float v = acc[i] + ldg<F32>(U_b, cU + i)
                    + part[i * 96 + cg] + part[768 + i * 96 + cg] + part[1536 + i * 96 + cg];
            v = gelu_exact(v);
            hv[i] = v;
            if (cg >= 48) { s1 += v; s2 += v * v; }
        }
        if (cg < 48) {
            *(float4*)(xh + (size_t)r * ZDIM + cU)     = make_float4(hv[0], hv[1], hv[2], hv[3]);
            *(float4*)(xh + (size_t)r * ZDIM + cU + 4) = make_float4(hv[4], hv[5], hv[6], hv[7]);
        }
    }

    // ---------- LayerNorm ----------
    const float2 S = block_sum2(s1, s2, sm);
    const float mu = S.x * (1.0f / ZDIM);
    const float rs = rsqrtf(S.y * (1.0f / ZDIM) - mu * mu + 1e-5f);
    if (kh == 0 && cg >= 48) {
        #pragma unroll
        for (int i = 0; i < 8; i++) {
            const int zc = cU - ZDIM + i;
            zs[zc] = (hv[i] - mu) * rs * ldg<F32>(ln_w, zc) + ldg<F32>(ln_b, zc);
        }
    }
    __syncthreads();

    // ---------- encoder: cgE=t%48 -> 4 cols of 192; khE=t/48 -> K chunk 48 ----------
    {
        const int cgE = t % 48, khE = t / 48;
        const int cE = 4 * cgE, kbE = 48 * khE;
        float ea[4] = {0,0,0,0};
        V4<F32> va[8], vb[8];
        #pragma unroll
        for (int j = 0; j < 8; j++) va[j].load(enc_w, (size_t)(kbE + j) * HID + cE);
        for (int k0 = kbE; k0 < kbE + 48; k0 += 16) {
            #pragma unroll
            for (int j = 0; j < 8; j++) vb[j].load(enc_w, (size_t)(k0 + 8 + j) * HID + cE);
            #pragma unroll
            for (int j = 0; j < 8; j++) {
                const float zv = zs[k0 + j];
                #pragma unroll
                for (int i = 0; i < 4; i++) ea[i] = fmaf(zv, va[j].g(i), ea[i]);
            }
            if (k0 + 16 < kbE + 48) {
                #pragma unroll
                for (int j = 0; j < 8; j++) va[j].load(enc_w, (size_t)(k0 + 16 + j) * HID + cE);
            }
            #pragma unroll
            for (int j = 0; j < 8; j++) {
                const float zv = zs[k0 + 8 + j];
                #pragma unroll
                for (int i = 0; i < 4; i++) ea[i] = fmaf(zv, vb[j].g(i), ea[i]);
            }
        }
        if (khE > 0) {
            float* p = &part[(khE - 1) * 192 + cgE];
            #pragma unroll
            for (int i = 0; i < 4; i++) p[i * 48] = ea[i];
        }
        __syncthreads();
        if (khE == 0) {
            #pragma unroll
            for (int i = 0; i < 4; i++) {
                float v = ea[i] + ldg<F32>(enc_b, cE + i);
                #pragma unroll
                for (int kk = 0; kk < 7; kk++) v += part[kk * 192 + i * 48 + cgE];
                hid[cE + i] = gelu_exact(v);
            }
        }
        __syncthreads();
    }

    // ---------- decoder: cgD=t%96 -> 4 cols of 384; khD=t/96 -> K chunk 48 ----------
    {
        const int cgD = t % 96, khD = t / 96;
        const int cD = 4 * cgD, kbD = 48 * khD;
        float aa[4] = {0,0,0,0}, ac[4] = {0,0,0,0};
        V4<F32> va[8], vb[8];
        #pragma unroll
        for (int j = 0; j < 8; j++) va[j].load(dec_w, (size_t)(kbD + j) * ZDIM + cD);
        for (int k0 = kbD; k0 < kbD + 48; k0 += 16) {
            #pragma unroll
            for (int j = 0; j < 8; j++) vb[j].load(dec_w, (size_t)(k0 + 8 + j) * ZDIM + cD);
            #pragma unroll
            for (int j = 0; j < 8; j++) {
                const float hvv = hid[k0 + j], gv = gh[k0 + j];
                #pragma unroll
                for (int i = 0; i < 4; i++) {
                    const float w = va[j].g(i);
                    aa[i] = fmaf(hvv, w, aa[i]);
                    ac[i] = fmaf(gv, w, ac[i]);
                }
            }
            if (k0 + 16 < kbD + 48) {
                #pragma unroll
                for (int j = 0; j < 8; j++) va[j].load(dec_w, (size_t)(k0 + 16 + j) * ZDIM + cD);
            }
            #pragma unroll
            for (int j = 0; j < 8; j++) {
                const float hvv = hid[k0 + 8 + j], gv = gh[k0 + 8 + j];
                #pragma unroll
                for (int i = 0; i < 4; i++) {
                    const float w = vb[j].g(i);
                    aa[i] = fmaf(hvv, w, aa[i]);
                    ac[i] = fmaf(gv, w, ac[i]);
                }
            }
        }
        if (khD > 0) {
            float* p = &part[(khD - 1) * 768 + cgD];
            #pragma unroll
            for (int i = 0; i < 4; i++) { p[i * 96] = aa[i]; p[384 + i * 96] = ac[i]; }
        }
        __syncthreads();
        float pd = 0.f, pe = 0.f;
        if (khD == 0) {
            #pragma unroll
            for (int i = 0; i < 4; i++) {
                const int c = cD + i;
                const float dbv = ldg<F32>(dec_b, c);
                float v = aa[i] + dbv, w = ac[i] + dbv;
                #pragma unroll
                for (int kk = 0; kk < 3; kk++) {
                    v += part[kk * 768 + i * 96 + cgD];
                    w += part[kk * 768 + 384 + i * 96 + cgD];
                }
                const float zv = zs[c];
                pd = fmaf(v, zv, pd);
                pe = fmaf(w, zv, pe);
            }
        }
        const float2 D = block_sum2(pd, pe, sm);
        if (t == 0) { diag[r] = D.x; d0[r] = D.y; }
    }
}

__global__ __launch_bounds__(384) void k_rows(
    const void* x, const void* U_w, const void* U_b,
    const void* ln_w, const void* ln_b,
    const void* enc_w, const void* enc_b,
    const void* dec_w, const void* dec_b,
    float* xh, float* d0, float* diag)
{
    if (is_f32(ln_w))
        rows_body<true >(x, U_w, U_b, ln_w, ln_b, enc_w, enc_b, dec_w, dec_b, xh, d0, diag);
    else
        rows_body<false>(x, U_w, U_b, ln_w, ln_b, enc_w, enc_b, dec_w, dec_b, xh, d0, diag);
}

// ============ K2: 512 blocks, 1 row: batch stats + combine + V (split-K) ============
template<bool F32>
__device__ void out_body(
    const float* __restrict__ d0, const float* __restrict__ diag,
    const float* __restrict__ xh,
    const void* __restrict__ V_w, const void* __restrict__ V_b,
    void* __restrict__ out)
{
    const int r = blockIdx.x;
    const int b = r >> 7;
    const int t = threadIdx.x;
    __shared__ float e0s[NN];
    __shared__ float as[ZDIM];
    __shared__ float pv[7 * 384];
    __shared__ float sm[12];

    // batch softmax stats (redundant per block)
    float d0v = -INFINITY, dgv = -INFINITY;
    if (t < NN) { d0v = d0[b * NN + t]; dgv = diag[b * NN + t]; }
    const float m = block_max(fmaxf(d0v, dgv), sm);
    float e0v = 0.f;
    if (t < NN) { e0v = expf(d0v - m); e0s[t] = e0v; }
    const float S = block_sum(e0v, sm);

    const float e00 = expf(d0[r] - m);
    const float ed0 = expf(diag[r] - m);
    const float inv = 1.0f / (S - e00 + ed0);

    // base_t = sum_j e0s[j] * xh[b,j,t]  (16-deep ping-pong)
    float acc = 0.f;
    {
        const float* xp = xh + (size_t)b * NN * ZDIM + t;
        float wa[16], wb[16];
        #pragma unroll
        for (int j = 0; j < 16; j++) wa[j] = xp[(size_t)j * ZDIM];
        for (int j0 = 0; j0 < NN; j0 += 32) {
            #pragma unroll
            for (int j = 0; j < 16; j++) wb[j] = xp[(size_t)(j0 + 16 + j) * ZDIM];
            #pragma unroll
            for (int j = 0; j < 16; j++) acc = fmaf(e0s[j0 + j], wa[j], acc);
            if (j0 + 32 < NN) {
                #pragma unroll
                for (int j = 0; j < 16; j++) wa[j] = xp[(size_t)(j0 + 32 + j) * ZDIM];
            }
            #pragma unroll
            for (int j = 0; j < 16; j++) acc = fmaf(e0s[j0 + 16 + j], wb[j], acc);
        }
    }
    as[t] = (acc + (ed0 - e00) * xh[(size_t)r * ZDIM + t]) * inv;
    __syncthreads();

    // V: cg=t%48 -> 8 cols of 384; kh=t/48 -> K chunk of 48
    const int cg = t % 48, kh = t / 48;
    const int cV = 8 * cg, kb = 48 * kh;
    float a8[8] = {0,0,0,0,0,0,0,0};
    {
        V8<F32> va[8], vb[8];
        #pragma unroll
        for (int j = 0; j < 8; j++) va[j].load(V_w, (size_t)(kb + j) * FEAT + cV);
        for (int f0 = kb; f0 < kb + 48; f0 += 16) {
            #pragma unroll
            for (int j = 0; j < 8; j++) vb[j].load(V_w, (size_t)(f0 + 8 + j) * FEAT + cV);
            #pragma unroll
            for (int j = 0; j < 8; j++) {
                const float s0 = as[f0 + j];
                #pragma unroll
                for (int i = 0; i < 8; i++) a8[i] = fmaf(s0, va[j].g(i), a8[i]);
            }
            if (f0 + 16 < kb + 48) {
                #pragma unroll
                for (int j = 0; j < 8; j++) va[j].load(V_w, (size_t)(f0 + 16 + j) * FEAT + cV);
            }
            #pragma unroll
            for (int j = 0; j < 8; j++) {
                const float s0 = as[f0 + 8 + j];
                #pragma unroll
                for (int i = 0; i < 8; i++) a8[i] = fmaf(s0, vb[j].g(i), a8[i]);
            }
        }
    }
    if (kh > 0) {
        float* p = &pv[(kh - 1) * 384 + cg];
        #pragma unroll
        for (int i = 0; i < 8; i++) p[i * 48] = a8[i];   // transposed: conflict-free
    }
    __syncthreads();
    if (kh == 0) {
        float o[8];
        #pragma unroll
        for (int i = 0; i < 8; i++) {
            float u = a8[i] + ldg<F32>(V_b, cV + i);
            #pragma unroll
            for (int kk = 0; kk < 7; kk++) u += pv[kk * 384 + i * 48 + cg];
            o[i] = u;
        }
        st8<F32>(out, (size_t)r * FEAT + cV, o);
    }
}

__global__ __launch_bounds__(384) void k_out(
    const void* ln_w,
    const float* d0, const float* diag, const float* xh,
    const void* V_w, const void* V_b, void* out)
{
    if (is_f32(ln_w))
        out_body<true >(d0, diag, xh, V_w, V_b, out);
    else
        out_body<false>(d0, diag, xh, V_w, V_b, out);
}

extern "C" void kernel_launch(void* const* d_in, const int* in_sizes, int n_in,
                              void* d_out, int out_size, void* d_ws, size_t ws_size,
                              hipStream_t stream) {
    const void* x     = d_in[0];
    const void* U_w   = d_in[1];
    const void* U_b   = d_in[2];
    const void* ln_w  = d_in[3];
    const void* ln_b  = d_in[4];
    const void* enc_w = d_in[5];
    const void* enc_b = d_in[6];
    const void* dec_w = d_in[7];
    const void* dec_b = d_in[8];
    const void* V_w   = d_in[9];
    const void* V_b   = d_in[10];

    // workspace layout (fp32)
    float* ws   = (float*)d_ws;
    float* xh   = ws;                     // 512*384
    float* d0   = xh + (size_t)BN * ZDIM; // 512
    float* diag = d0 + BN;                // 512

    k_rows<<<BN, 384, 0, stream>>>(x, U_w, U_b, ln_w, ln_b, enc_w, enc_b,
                                   dec_w, dec_b, xh, d0, diag);
    k_out<<<BN, 384, 0, stream>>>(ln_w, d0, diag, xh, V_w, V_b, d_out);
}

// Round 9
// 111.186 us; speedup vs baseline: 1.4116x; 1.2462x over previous
//
#include <hip/hip_runtime.h>
#include <hip/hip_bf16.h>
#include <math.h>

#define FEAT 384
#define FFN  768
#define ZDIM 384
#define HID  192
#define BB   4
#define NN   128
#define BN   (BB*NN)   // 512 rows

__device__ __forceinline__ float gelu_exact(float x) {
    // jax.nn.gelu(approximate=False) == 0.5*x*(1+erf(x/sqrt(2)))
    return 0.5f * x * (1.0f + erff(x * 0.70710678118654752440f));
}

__device__ __forceinline__ float bflo(unsigned u) { return __uint_as_float(u << 16); }
__device__ __forceinline__ float bfhi(unsigned u) { return __uint_as_float(u & 0xFFFF0000u); }

template<bool F32>
__device__ __forceinline__ float ldg(const void* p, int i) {
    if constexpr (F32) return ((const float*)p)[i];
    return __uint_as_float(((unsigned)((const unsigned short*)p)[i]) << 16);
}

__device__ __forceinline__ unsigned pack2(float a, float b) {
    __hip_bfloat16 ba = __float2bfloat16(a), bb = __float2bfloat16(b);
    unsigned short ua, ub;
    __builtin_memcpy(&ua, &ba, 2);
    __builtin_memcpy(&ub, &bb, 2);
    return (unsigned)ua | ((unsigned)ub << 16);
}

template<bool F32>
__device__ __forceinline__ void st8(void* p, size_t off, const float v[8]) {
    if constexpr (F32) {
        *(float4*)((float*)p + off)     = make_float4(v[0], v[1], v[2], v[3]);
        *(float4*)((float*)p + off + 4) = make_float4(v[4], v[5], v[6], v[7]);
    } else {
        uint4 u;
        u.x = pack2(v[0], v[1]); u.y = pack2(v[2], v[3]);
        u.z = pack2(v[4], v[5]); u.w = pack2(v[6], v[7]);
        *(uint4*)((unsigned short*)p + off) = u;
    }
}

// 8-element weight vector: one 16B load (bf16) / two 16B loads (fp32)
template<bool F32> struct V8;
template<> struct V8<true> {
    float4 a, b;
    __device__ __forceinline__ void load(const void* p, size_t off) {
        a = *(const float4*)((const float*)p + off);
        b = *(const float4*)((const float*)p + off + 4);
    }
    __device__ __forceinline__ float g(int i) const {
        return (i < 4) ? (&a.x)[i] : (&b.x)[i - 4];
    }
};
template<> struct V8<false> {
    uint4 u;
    __device__ __forceinline__ void load(const void* p, size_t off) {
        u = *(const uint4*)((const unsigned short*)p + off);
    }
    __device__ __forceinline__ float g(int i) const {
        const unsigned w = (&u.x)[i >> 1];
        return (i & 1) ? bfhi(w) : bflo(w);
    }
};
// 4-element weight vector: 8B load (bf16) / 16B load (fp32)
template<bool F32> struct V4;
template<> struct V4<true> {
    float4 a;
    __device__ __forceinline__ void load(const void* p, size_t off) {
        a = *(const float4*)((const float*)p + off);
    }
    __device__ __forceinline__ float g(int i) const { return (&a.x)[i]; }
};
template<> struct V4<false> {
    uint2 u;
    __device__ __forceinline__ void load(const void* p, size_t off) {
        u = *(const uint2*)((const unsigned short*)p + off);
    }
    __device__ __forceinline__ float g(int i) const {
        const unsigned w = (&u.x)[i >> 1];
        return (i & 1) ? bfhi(w) : bflo(w);
    }
};

// dtype detect from ln_w (== ones): fp32 1.0f low u16 = 0x0000; bf16 = 0x3F80.
__device__ __forceinline__ bool is_f32(const void* ln_w) {
    return ((const unsigned short*)ln_w)[0] == 0;
}

// ---- block reductions over 384 threads (6 wave64); sm holds 12 floats ----
__device__ __forceinline__ float block_sum(float v, float* sm) {
    for (int o = 32; o > 0; o >>= 1) v += __shfl_down(v, o, 64);
    const int lane = threadIdx.x & 63, w = threadIdx.x >> 6;
    __syncthreads();
    if (lane == 0) sm[w] = v;
    __syncthreads();
    return sm[0] + sm[1] + sm[2] + sm[3] + sm[4] + sm[5];
}
__device__ __forceinline__ float2 block_sum2(float vx, float vy, float* sm) {
    for (int o = 32; o > 0; o >>= 1) {
        vx += __shfl_down(vx, o, 64);
        vy += __shfl_down(vy, o, 64);
    }
    const int lane = threadIdx.x & 63, w = threadIdx.x >> 6;
    __syncthreads();
    if (lane == 0) { sm[w] = vx; sm[w + 6] = vy; }
    __syncthreads();
    return make_float2(sm[0] + sm[1] + sm[2] + sm[3] + sm[4] + sm[5],
                       sm[6] + sm[7] + sm[8] + sm[9] + sm[10] + sm[11]);
}
__device__ __forceinline__ float block_max(float v, float* sm) {
    for (int o = 32; o > 0; o >>= 1) v = fmaxf(v, __shfl_down(v, o, 64));
    const int lane = threadIdx.x & 63, w = threadIdx.x >> 6;
    __syncthreads();
    if (lane == 0) sm[w] = v;
    __syncthreads();
    return fmaxf(fmaxf(fmaxf(sm[0], sm[1]), fmaxf(sm[2], sm[3])), fmaxf(sm[4], sm[5]));
}

// ============ K1: 256 blocks, 2 rows each: U + LN + AE + dots ============
// split-K on every GEMM; conflict-free transposed partials part[kh][i*G + cg]
template<bool F32>
__device__ void rows_body(
    const void* __restrict__ x, const void* __restrict__ U_w,
    const void* __restrict__ U_b, const void* __restrict__ ln_w,
    const void* __restrict__ ln_b, const void* __restrict__ enc_w,
    const void* __restrict__ enc_b, const void* __restrict__ dec_w,
    const void* __restrict__ dec_b,
    float* __restrict__ xh, float* __restrict__ d0, float* __restrict__ diag)
{
    const int r0 = 2 * blockIdx.x, r1 = r0 + 1;
    const int t = threadIdx.x;
    __shared__ float xs[2][FEAT];
    __shared__ float zs[2][ZDIM];
    __shared__ float hid[2][HID];
    __shared__ float gh[HID];
    __shared__ float part[4608];   // U: 3*1536, enc: 7*384, dec: 3*1152
    __shared__ float sm[12];

    xs[0][t] = ldg<F32>(x, r0 * FEAT + t);
    xs[1][t] = ldg<F32>(x, r1 * FEAT + t);
    if (t < HID) gh[t] = gelu_exact(ldg<F32>(enc_b, t));   // for AE(0)
    __syncthreads();

    // ---------- U: cg=t%96 -> 8 cols of 768; kh=t/96 -> K chunk of 96 ----------
    const int cg = t % 96, kh = t / 96;
    const int cU = 8 * cg;
    const int kb = 96 * kh;
    float acc0[8] = {0,0,0,0,0,0,0,0}, acc1[8] = {0,0,0,0,0,0,0,0};
    {
        V8<F32> wa[8], wb[8];
        #pragma unroll
        for (int j = 0; j < 8; j++) wa[j].load(U_w, (size_t)(kb + j) * FFN + cU);
        for (int k0 = kb; k0 < kb + 96; k0 += 16) {
            #pragma unroll
            for (int j = 0; j < 8; j++) wb[j].load(U_w, (size_t)(k0 + 8 + j) * FFN + cU);
            #pragma unroll
            for (int j = 0; j < 8; j++) {
                const float x0 = xs[0][k0 + j], x1 = xs[1][k0 + j];
                #pragma unroll
                for (int i = 0; i < 8; i++) {
                    const float w = wa[j].g(i);
                    acc0[i] = fmaf(x0, w, acc0[i]);
                    acc1[i] = fmaf(x1, w, acc1[i]);
                }
            }
            if (k0 + 16 < kb + 96) {
                #pragma unroll
                for (int j = 0; j < 8; j++) wa[j].load(U_w, (size_t)(k0 + 16 + j) * FFN + cU);
            }
            #pragma unroll
            for (int j = 0; j < 8; j++) {
                const float x0 = xs[0][k0 + 8 + j], x1 = xs[1][k0 + 8 + j];
                #pragma unroll
                for (int i = 0; i < 8; i++) {
                    const float w = wb[j].g(i);
                    acc0[i] = fmaf(x0, w, acc0[i]);
                    acc1[i] = fmaf(x1, w, acc1[i]);
                }
            }
        }
    }
    if (kh > 0) {
        float* p = &part[(kh - 1) * 1536 + cg];
        #pragma unroll
        for (int i = 0; i < 8; i++) { p[i * 96] = acc0[i]; p[768 + i * 96] = acc1[i]; }
    }
    __syncthreads();

    float h0[8], h1[8];
    float s1a = 0.f, s1b = 0.f, s2a = 0.f, s2b = 0.f;
    if (kh == 0) {
        #pragma unroll
        for (int i = 0; i < 8; i++) {
            const float ub = ldg<F32>(U_b, cU + i);
            float v0 = acc0[i] + ub, v1 = acc1[i] + ub;
            #pragma unroll
            for (int kk = 0; kk < 3; kk++) {
                v0 += part[kk * 1536 + i * 96 + cg];
                v1 += part[kk * 1536 + 768 + i * 96 + cg];
            }
            v0 = gelu_exact(v0); v1 = gelu_exact(v1);
            h0[i] = v0; h1[i] = v1;
            if (cg >= 48) { s1a += v0; s2a += v0 * v0; s1b += v1; s2b += v1 * v1; }
        }
        if (cg < 48) {   // xh half -> fp32 workspace
            *(float4*)(xh + (size_t)r0 * ZDIM + cU)     = make_float4(h0[0], h0[1], h0[2], h0[3]);
            *(float4*)(xh + (size_t)r0 * ZDIM + cU + 4) = make_float4(h0[4], h0[5], h0[6], h0[7]);
            *(float4*)(xh + (size_t)r1 * ZDIM + cU)     = make_float4(h1[0], h1[1], h1[2], h1[3]);
            *(float4*)(xh + (size_t)r1 * ZDIM + cU + 4) = make_float4(h1[4], h1[5], h1[6], h1[7]);
        }
    }

    // ---------- LayerNorm (both rows) ----------
    const float2 S1 = block_sum2(s1a, s1b, sm);
    const float2 S2 = block_sum2(s2a, s2b, sm);
    const float mu0 = S1.x * (1.0f / ZDIM), mu1 = S1.y * (1.0f / ZDIM);
    const float rs0 = rsqrtf(S2.x * (1.0f / ZDIM) - mu0 * mu0 + 1e-5f);
    const float rs1 = rsqrtf(S2.y * (1.0f / ZDIM) - mu1 * mu1 + 1e-5f);
    if (kh == 0 && cg >= 48) {
        #pragma unroll
        for (int i = 0; i < 8; i++) {
            const int zc = cU - ZDIM + i;
            const float w = ldg<F32>(ln_w, zc), bb = ldg<F32>(ln_b, zc);
            zs[0][zc] = (h0[i] - mu0) * rs0 * w + bb;
            zs[1][zc] = (h1[i] - mu1) * rs1 * w + bb;
        }
    }
    __syncthreads();

    // ---------- encoder: cgE=t%48 -> 4 cols of 192; khE=t/48 -> K chunk 48 ----------
    {
        const int cgE = t % 48, khE = t / 48;
        const int cE = 4 * cgE, kbE = 48 * khE;
        float e0a[4] = {0,0,0,0}, e1a[4] = {0,0,0,0};
        V4<F32> va[8], vb[8];
        #pragma unroll
        for (int j = 0; j < 8; j++) va[j].load(enc_w, (size_t)(kbE + j) * HID + cE);
        for (int k0 = kbE; k0 < kbE + 48; k0 += 16) {
            #pragma unroll
            for (int j = 0; j < 8; j++) vb[j].load(enc_w, (size_t)(k0 + 8 + j) * HID + cE);
            #pragma unroll
            for (int j = 0; j < 8; j++) {
                const float z0 = zs[0][k0 + j], z1 = zs[1][k0 + j];
                #pragma unroll
                for (int i = 0; i < 4; i++) {
                    const float w = va[j].g(i);
                    e0a[i] = fmaf(z0, w, e0a[i]);
                    e1a[i] = fmaf(z1, w, e1a[i]);
                }
            }
            if (k0 + 16 < kbE + 48) {
                #pragma unroll
                for (int j = 0; j < 8; j++) va[j].load(enc_w, (size_t)(k0 + 16 + j) * HID + cE);
            }
            #pragma unroll
            for (int j = 0; j < 8; j++) {
                const float z0 = zs[0][k0 + 8 + j], z1 = zs[1][k0 + 8 + j];
                #pragma unroll
                for (int i = 0; i < 4; i++) {
                    const float w = vb[j].g(i);
                    e0a[i] = fmaf(z0, w, e0a[i]);
                    e1a[i] = fmaf(z1, w, e1a[i]);
                }
            }
        }
        if (khE > 0) {
            float* p = &part[(khE - 1) * 384 + cgE];
            #pragma unroll
            for (int i = 0; i < 4; i++) { p[i * 48] = e0a[i]; p[192 + i * 48] = e1a[i]; }
        }
        __syncthreads();
        if (khE == 0) {
            #pragma unroll
            for (int i = 0; i < 4; i++) {
                const float ebv = ldg<F32>(enc_b, cE + i);
                float v0 = e0a[i] + ebv, v1 = e1a[i] + ebv;
                #pragma unroll
                for (int kk = 0; kk < 7; kk++) {
                    v0 += part[kk * 384 + i * 48 + cgE];
                    v1 += part[kk * 384 + 192 + i * 48 + cgE];
                }
                hid[0][cE + i] = gelu_exact(v0);
                hid[1][cE + i] = gelu_exact(v1);
            }
        }
        __syncthreads();
    }

    // ---------- decoder: cgD=t%96 -> 4 cols of 384; khD=t/96 -> K chunk 48 ----------
    {
        const int cgD = t % 96, khD = t / 96;
        const int cD = 4 * cgD, kbD = 48 * khD;
        float aa[4] = {0,0,0,0}, ab_[4] = {0,0,0,0}, ac[4] = {0,0,0,0};
        V4<F32> va[8], vb[8];
        #pragma unroll
        for (int j = 0; j < 8; j++) va[j].load(dec_w, (size_t)(kbD + j) * ZDIM + cD);
        for (int k0 = kbD; k0 < kbD + 48; k0 += 16) {
            #pragma unroll
            for (int j = 0; j < 8; j++) vb[j].load(dec_w, (size_t)(k0 + 8 + j) * ZDIM + cD);
            #pragma unroll
            for (int j = 0; j < 8; j++) {
                const float v0 = hid[0][k0 + j], v1 = hid[1][k0 + j], gv = gh[k0 + j];
                #pragma unroll
                for (int i = 0; i < 4; i++) {
                    const float w = va[j].g(i);
                    aa[i] = fmaf(v0, w, aa[i]);
                    ab_[i] = fmaf(v1, w, ab_[i]);
                    ac[i] = fmaf(gv, w, ac[i]);
                }
            }
            if (k0 + 16 < kbD + 48) {
                #pragma unroll
                for (int j = 0; j < 8; j++) va[j].load(dec_w, (size_t)(k0 + 16 + j) * ZDIM + cD);
            }
            #pragma unroll
            for (int j = 0; j < 8; j++) {
                const float v0 = hid[0][k0 + 8 + j], v1 = hid[1][k0 + 8 + j], gv = gh[k0 + 8 + j];
                #pragma unroll
                for (int i = 0; i < 4; i++) {
                    const float w = vb[j].g(i);
                    aa[i] = fmaf(v0, w, aa[i]);
                    ab_[i] = fmaf(v1, w, ab_[i]);
                    ac[i] = fmaf(gv, w, ac[i]);
                }
            }
        }
        if (khD > 0) {
            float* p = &part[(khD - 1) * 1152 + cgD];
            #pragma unroll
            for (int i = 0; i < 4; i++) {
                p[i * 96] = aa[i];
                p[384 + i * 96] = ab_[i];
                p[768 + i * 96] = ac[i];
            }
        }
        __syncthreads();
        float pd0 = 0.f, pd1 = 0.f, pe0 = 0.f, pe1 = 0.f;
        if (khD == 0) {
            #pragma unroll
            for (int i = 0; i < 4; i++) {
                const int c = cD + i;
                const float dbv = ldg<F32>(dec_b, c);
                float v0 = aa[i] + dbv, v1 = ab_[i] + dbv, v2 = ac[i] + dbv;
                #pragma unroll
                for (int kk = 0; kk < 3; kk++) {
                    v0 += part[kk * 1152 + i * 96 + cgD];
                    v1 += part[kk * 1152 + 384 + i * 96 + cgD];
                    v2 += part[kk * 1152 + 768 + i * 96 + cgD];
                }
                const float z0 = zs[0][c], z1 = zs[1][c];
                pd0 = fmaf(v0, z0, pd0);
                pd1 = fmaf(v1, z1, pd1);
                pe0 = fmaf(v2, z0, pe0);
                pe1 = fmaf(v2, z1, pe1);
            }
        }
        const float2 DG = block_sum2(pd0, pd1, sm);
        const float2 DD = block_sum2(pe0, pe1, sm);
        if (t == 0) {
            diag[r0] = DG.x; diag[r1] = DG.y;
            d0[r0] = DD.x;   d0[r1] = DD.y;
        }
    }
}

__global__ __launch_bounds__(384) void k_rows(
    const void* x, const void* U_w, const void* U_b,
    const void* ln_w, const void* ln_b,
    const void* enc_w, const void* enc_b,
    const void* dec_w, const void* dec_b,
    float* xh, float* d0, float* diag)
{
    if (is_f32(ln_w))
        rows_body<true >(x, U_w, U_b, ln_w, ln_b, enc_w, enc_b, dec_w, dec_b, xh, d0, diag);
    else
        rows_body<false>(x, U_w, U_b, ln_w, ln_b, enc_w, enc_b, dec_w, dec_b, xh, d0, diag);
}

// ============ K2: 256 blocks, 2 rows: batch stats + combine + V (split-K) ============
template<bool F32>
__device__ void out_body(
    const float* __restrict__ d0, const float* __restrict__ diag,
    const float* __restrict__ xh,
    const void* __restrict__ V_w, const void* __restrict__ V_b,
    void* __restrict__ out)
{
    const int r0 = 2 * blockIdx.x, r1 = r0 + 1;
    const int b = r0 >> 7;
    const int t = threadIdx.x;
    __shared__ float e0s[NN];
    __shared__ float as[2][ZDIM];
    __shared__ float pv[5376];   // 7 * 768
    __shared__ float sm[12];

    // batch softmax stats (redundant per block)
    float d0v = -INFINITY, dgv = -INFINITY;
    if (t < NN) { d0v = d0[b * NN + t]; dgv = diag[b * NN + t]; }
    const float m = block_max(fmaxf(d0v, dgv), sm);
    float e0v = 0.f;
    if (t < NN) { e0v = expf(d0v - m); e0s[t] = e0v; }
    const float S = block_sum(e0v, sm);

    const float e00 = expf(d0[r0] - m), e01 = expf(d0[r1] - m);
    const float ed0 = expf(diag[r0] - m), ed1 = expf(diag[r1] - m);
    const float inv0 = 1.0f / (S - e00 + ed0);
    const float inv1 = 1.0f / (S - e01 + ed1);

    // base_t = sum_j e0s[j] * xh[b,j,t]  (row-independent; 16-deep ping-pong)
    float acc = 0.f;
    {
        const float* xp = xh + (size_t)b * NN * ZDIM + t;
        float wa[16], wb[16];
        #pragma unroll
        for (int j = 0; j < 16; j++) wa[j] = xp[(size_t)j * ZDIM];
        for (int j0 = 0; j0 < NN; j0 += 32) {
            #pragma unroll
            for (int j = 0; j < 16; j++) wb[j] = xp[(size_t)(j0 + 16 + j) * ZDIM];
            #pragma unroll
            for (int j = 0; j < 16; j++) acc = fmaf(e0s[j0 + j], wa[j], acc);
            if (j0 + 32 < NN) {
                #pragma unroll
                for (int j = 0; j < 16; j++) wa[j] = xp[(size_t)(j0 + 32 + j) * ZDIM];
            }
            #pragma unroll
            for (int j = 0; j < 16; j++) acc = fmaf(e0s[j0 + 16 + j], wb[j], acc);
        }
    }
    as[0][t] = (acc + (ed0 - e00) * xh[(size_t)r0 * ZDIM + t]) * inv0;
    as[1][t] = (acc + (ed1 - e01) * xh[(size_t)r1 * ZDIM + t]) * inv1;
    __syncthreads();

    // V: cg=t%48 -> 8 cols of 384; kh=t/48 -> K chunk of 48; both rows
    const int cg = t % 48, kh = t / 48;
    const int cV = 8 * cg, kb = 48 * kh;
    float a0[8] = {0,0,0,0,0,0,0,0}, a1[8] = {0,0,0,0,0,0,0,0};
    {
        V8<F32> va[8], vb[8];
        #pragma unroll
        for (int j = 0; j < 8; j++) va[j].load(V_w, (size_t)(kb + j) * FEAT + cV);
        for (int f0 = kb; f0 < kb + 48; f0 += 16) {
            #pragma unroll
            for (int j = 0; j < 8; j++) vb[j].load(V_w, (size_t)(f0 + 8 + j) * FEAT + cV);
            #pragma unroll
            for (int j = 0; j < 8; j++) {
                const float s0 = as[0][f0 + j], s1 = as[1][f0 + j];
                #pragma unroll
                for (int i = 0; i < 8; i++) {
                    const float w = va[j].g(i);
                    a0[i] = fmaf(s0, w, a0[i]);
                    a1[i] = fmaf(s1, w, a1[i]);
                }
            }
            if (f0 + 16 < kb + 48) {
                #pragma unroll
                for (int j = 0; j < 8; j++) va[j].load(V_w, (size_t)(f0 + 16 + j) * FEAT + cV);
            }
            #pragma unroll
            for (int j = 0; j < 8; j++) {
                const float s0 = as[0][f0 + 8 + j], s1 = as[1][f0 + 8 + j];
                #pragma unroll
                for (int i = 0; i < 8; i++) {
                    const float w = vb[j].g(i);
                    a0[i] = fmaf(s0, w, a0[i]);
                    a1[i] = fmaf(s1, w, a1[i]);
                }
            }
        }
    }
    if (kh > 0) {
        float* p = &pv[(kh - 1) * 768 + cg];
        #pragma unroll
        for (int i = 0; i < 8; i++) { p[i * 48] = a0[i]; p[384 + i * 48] = a1[i]; }
    }
    __syncthreads();
    if (kh == 0) {
        float o0[8], o1[8];
        #pragma unroll
        for (int i = 0; i < 8; i++) {
            const float vb_ = ldg<F32>(V_b, cV + i);
            float u0 = a0[i] + vb_, u1 = a1[i] + vb_;
            #pragma unroll
            for (int kk = 0; kk < 7; kk++) {
                u0 += pv[kk * 768 + i * 48 + cg];
                u1 += pv[kk * 768 + 384 + i * 48 + cg];
            }
            o0[i] = u0; o1[i] = u1;
        }
        st8<F32>(out, (size_t)r0 * FEAT + cV, o0);
        st8<F32>(out, (size_t)r1 * FEAT + cV, o1);
    }
}

__global__ __launch_bounds__(384) void k_out(
    const void* ln_w,
    const float* d0, const float* diag, const float* xh,
    const void* V_w, const void* V_b, void* out)
{
    if (is_f32(ln_w))
        out_body<true >(d0, diag, xh, V_w, V_b, out);
    else
        out_body<false>(d0, diag, xh, V_w, V_b, out);
}

extern "C" void kernel_launch(void* const* d_in, const int* in_sizes, int n_in,
                              void* d_out, int out_size, void* d_ws, size_t ws_size,
                              hipStream_t stream) {
    const void* x     = d_in[0];
    const void* U_w   = d_in[1];
    const void* U_b   = d_in[2];
    const void* ln_w  = d_in[3];
    const void* ln_b  = d_in[4];
    const void* enc_w = d_in[5];
    const void* enc_b = d_in[6];
    const void* dec_w = d_in[7];
    const void* dec_b = d_in[8];
    const void* V_w   = d_in[9];
    const void* V_b   = d_in[10];

    // workspace layout (fp32)
    float* ws   = (float*)d_ws;
    float* xh   = ws;                     // 512*384
    float* d0   = xh + (size_t)BN * ZDIM; // 512
    float* diag = d0 + BN;                // 512

    k_rows<<<BN / 2, 384, 0, stream>>>(x, U_w, U_b, ln_w, ln_b, enc_w, enc_b,
                                       dec_w, dec_b, xh, d0, diag);
    k_out<<<BN / 2, 384, 0, stream>>>(ln_w, d0, diag, xh, V_w, V_b, d_out);
}